// Round 1
// baseline (1562.077 us; speedup 1.0000x reference)
//
#include <hip/hip_runtime.h>
#include <math.h>

// Problem constants
namespace {
constexpr int B_N  = 32;    // batch
constexpr int SEQ  = 1024;  // N
constexpr int AG   = 256;   // agents A
constexpr int D    = 256;   // D_IN == D_H
constexpr int NH   = 8;     // heads
constexpr float SCALE = 0.0625f;   // 1/sqrt(256)
constexpr float EPS   = 1e-12f;

// workspace layout (floats). Total = 25,690,112 floats = ~98 MB.
constexpr size_t H_OFF = 0;                               // h: B*SEQ*D
constexpr size_t M_OFF = (size_t)B_N * SEQ * D;           // M: NH*D*D
constexpr size_t Z_OFF = M_OFF + (size_t)NH * D * D;      // z': B*NH*AG*D
}

// ---------------------------------------------------------------------------
// Generic 64x64-tile NT GEMM, K=256, all leading dims = 256.
// C[row,col] = sum_k op(A[row,k]) * B[col,k]  (+ bias[col])
// Used for: encoder (LRELU+BIAS) and M_h = WQ_h @ WK_h^T (plain).
// ---------------------------------------------------------------------------
template<bool LRELU, bool BIAS>
__global__ __launch_bounds__(256) void gemm_nt64(
    const float* __restrict__ Abase, const float* __restrict__ Bbase,
    const float* __restrict__ bias, float* __restrict__ Cbase,
    size_t za, size_t zb, size_t zc)
{
    __shared__ float AsT[32][68];   // [k][row]
    __shared__ float BsT[32][68];   // [k][col]
    const int t  = threadIdx.x;
    const int tx = t & 15, ty = t >> 4;
    const int col0 = blockIdx.x * 64;
    const int row0 = blockIdx.y * 64;
    const float* A  = Abase + za * blockIdx.z;
    const float* Bm = Bbase + zb * blockIdx.z;
    float* C        = Cbase + zc * blockIdx.z;

    float acc[4][4];
#pragma unroll
    for (int r = 0; r < 4; ++r)
#pragma unroll
        for (int c = 0; c < 4; ++c) acc[r][c] = 0.f;

    for (int k0 = 0; k0 < 256; k0 += 32) {
        __syncthreads();
#pragma unroll
        for (int ss = 0; ss < 2; ++ss) {
            int flat = t + 256 * ss;
            int rr = flat >> 3;      // 0..63
            int k4 = flat & 7;       // 0..7
            float4 v = *(const float4*)(A + (size_t)(row0 + rr) * 256 + k0 + k4 * 4);
            if (LRELU) {
                v.x = v.x > 0.f ? v.x : 0.01f * v.x;
                v.y = v.y > 0.f ? v.y : 0.01f * v.y;
                v.z = v.z > 0.f ? v.z : 0.01f * v.z;
                v.w = v.w > 0.f ? v.w : 0.01f * v.w;
            }
            AsT[k4*4+0][rr] = v.x; AsT[k4*4+1][rr] = v.y;
            AsT[k4*4+2][rr] = v.z; AsT[k4*4+3][rr] = v.w;
            float4 w = *(const float4*)(Bm + (size_t)(col0 + rr) * 256 + k0 + k4 * 4);
            BsT[k4*4+0][rr] = w.x; BsT[k4*4+1][rr] = w.y;
            BsT[k4*4+2][rr] = w.z; BsT[k4*4+3][rr] = w.w;
        }
        __syncthreads();
#pragma unroll 8
        for (int kk = 0; kk < 32; ++kk) {
            float4 a4 = *(const float4*)&AsT[kk][ty * 4];
            float4 b4 = *(const float4*)&BsT[kk][tx * 4];
            const float ar[4] = {a4.x, a4.y, a4.z, a4.w};
            const float bc[4] = {b4.x, b4.y, b4.z, b4.w};
#pragma unroll
            for (int r = 0; r < 4; ++r)
#pragma unroll
                for (int c = 0; c < 4; ++c)
                    acc[r][c] = fmaf(ar[r], bc[c], acc[r][c]);
        }
    }

    float4 bv = make_float4(0.f, 0.f, 0.f, 0.f);
    if (BIAS) bv = *(const float4*)(bias + col0 + tx * 4);
#pragma unroll
    for (int r = 0; r < 4; ++r) {
        float4 o;
        o.x = acc[r][0] + bv.x; o.y = acc[r][1] + bv.y;
        o.z = acc[r][2] + bv.z; o.w = acc[r][3] + bv.w;
        *(float4*)(C + (size_t)(row0 + ty * 4 + r) * 256 + col0 + tx * 4) = o;
    }
}

// ---------------------------------------------------------------------------
// Attention kernel: one block = (b, head, 64-row a-tile).
//  Phase 0: Q'[64x256] = ha @ M_h   (kept in registers, 64/thread)
//  Phase 1: flash loop over 16 n-tiles of 64:
//      S = Q' @ h_tile^T * SCALE  (d chunked by 64 through LDS)
//      online masked softmax tracking (max_all, Z_all, Z_masked)
//      z' += p @ h_tile           (d chunked by 64)
//  Epilogue: z'[b,h,a,d] = z'num / (Zm + EPS*Zall)
// LDS = 3 * 64*68*4 = 52,224 B -> 2 blocks/CU.
// ---------------------------------------------------------------------------
__global__ __launch_bounds__(256, 2) void attn_kernel(
    const float* __restrict__ h, const float* __restrict__ Mw,
    const float* __restrict__ msk, float* __restrict__ zout)
{
    __shared__ float As[64][68];   // Q' chunk, [d_local][a_local]
    __shared__ float Bs[64][68];   // h chunk,  [d_local][n_local]
    __shared__ float Ps[64][68];   // masked-exp p, row-permuted: row = 16*r + ty
    const int t  = threadIdx.x;
    const int tx = t & 15, ty = t >> 4;
    const int a0 = blockIdx.x * 64;
    const int hh = blockIdx.y;
    const int b  = blockIdx.z;
    const float* hb = h  + (size_t)b  * SEQ * D;
    const float* Mh = Mw + (size_t)hh * D * D;

    // ---- Phase 0: Q' tile in registers. qacc[r][q*4+c] -> d' = 64q + 4tx + c
    float qacc[4][16];
#pragma unroll
    for (int r = 0; r < 4; ++r)
#pragma unroll
        for (int j = 0; j < 16; ++j) qacc[r][j] = 0.f;

    for (int kc = 0; kc < 4; ++kc) {
        __syncthreads();
#pragma unroll
        for (int i = 0; i < 4; ++i) {              // stage haT chunk into Bs
            int nl = (t >> 4) + 16 * i;
            int d4 = t & 15;
            float4 v = *(const float4*)(hb + (size_t)(a0 + nl) * D + kc * 64 + d4 * 4);
            Bs[d4*4+0][nl] = v.x; Bs[d4*4+1][nl] = v.y;
            Bs[d4*4+2][nl] = v.z; Bs[d4*4+3][nl] = v.w;
        }
        __syncthreads();
        for (int dl = 0; dl < 64; ++dl) {
            float4 a4 = *(const float4*)&Bs[dl][ty * 4];
            const float ar[4] = {a4.x, a4.y, a4.z, a4.w};
            const float* Mrow = Mh + (size_t)(kc * 64 + dl) * D;
#pragma unroll
            for (int q = 0; q < 4; ++q) {
                float4 m4 = *(const float4*)(Mrow + q * 64 + tx * 4);
#pragma unroll
                for (int r = 0; r < 4; ++r) {
                    qacc[r][q*4+0] = fmaf(ar[r], m4.x, qacc[r][q*4+0]);
                    qacc[r][q*4+1] = fmaf(ar[r], m4.y, qacc[r][q*4+1]);
                    qacc[r][q*4+2] = fmaf(ar[r], m4.z, qacc[r][q*4+2]);
                    qacc[r][q*4+3] = fmaf(ar[r], m4.w, qacc[r][q*4+3]);
                }
            }
        }
    }

    // ---- Phase 1: flash loop. zacc[r][dc*4+c] -> d = 64*dc + tx + 16*c
    float zacc[4][16];
    float mx[4], Za[4], Zm[4];
#pragma unroll
    for (int r = 0; r < 4; ++r) {
        mx[r] = -INFINITY; Za[r] = 0.f; Zm[r] = 0.f;
#pragma unroll
        for (int j = 0; j < 16; ++j) zacc[r][j] = 0.f;
    }

    for (int nt = 0; nt < 16; ++nt) {
        const int n0 = nt * 64;
        float s[4][4];
#pragma unroll
        for (int r = 0; r < 4; ++r) { s[r][0]=0.f; s[r][1]=0.f; s[r][2]=0.f; s[r][3]=0.f; }

        // S = Q' @ h^T, chunked over d
        for (int dc = 0; dc < 4; ++dc) {
            __syncthreads();
#pragma unroll
            for (int r = 0; r < 4; ++r)
#pragma unroll
                for (int c = 0; c < 4; ++c)
                    As[tx*4+c][ty*4+r] = qacc[r][dc*4+c];
#pragma unroll
            for (int i = 0; i < 4; ++i) {
                int nl = (t >> 4) + 16 * i;
                int d4 = t & 15;
                float4 v = *(const float4*)(hb + (size_t)(n0 + nl) * D + dc * 64 + d4 * 4);
                Bs[d4*4+0][nl] = v.x; Bs[d4*4+1][nl] = v.y;
                Bs[d4*4+2][nl] = v.z; Bs[d4*4+3][nl] = v.w;
            }
            __syncthreads();
#pragma unroll 4
            for (int dl = 0; dl < 64; ++dl) {
                float4 a4 = *(const float4*)&As[dl][ty * 4];
                float4 b4 = *(const float4*)&Bs[dl][tx * 4];
                const float ar[4] = {a4.x, a4.y, a4.z, a4.w};
                const float bc[4] = {b4.x, b4.y, b4.z, b4.w};
#pragma unroll
                for (int r = 0; r < 4; ++r)
#pragma unroll
                    for (int c = 0; c < 4; ++c)
                        s[r][c] = fmaf(ar[r], bc[c], s[r][c]);
            }
        }

        // online masked softmax (per row a = 4*ty + r; 16 tx lanes hold the 64 cols)
#pragma unroll
        for (int r = 0; r < 4; ++r) {
            const int a = a0 + ty * 4 + r;
            float4 mv = *(const float4*)(msk + ((size_t)b * AG + a) * SEQ + n0 + tx * 4);
            float l0 = s[r][0]*SCALE, l1 = s[r][1]*SCALE, l2 = s[r][2]*SCALE, l3 = s[r][3]*SCALE;
            float mt = fmaxf(fmaxf(l0, l1), fmaxf(l2, l3));
#pragma unroll
            for (int off = 1; off < 16; off <<= 1)
                mt = fmaxf(mt, __shfl_xor(mt, off));
            float mxn   = fmaxf(mx[r], mt);
            float alpha = __expf(mx[r] - mxn);
            float e0 = __expf(l0 - mxn), e1 = __expf(l1 - mxn);
            float e2 = __expf(l2 - mxn), e3 = __expf(l3 - mxn);
            float p0 = mv.x * e0, p1 = mv.y * e1, p2 = mv.z * e2, p3 = mv.w * e3;
            float za_t = (e0 + e1) + (e2 + e3);
            float zm_t = (p0 + p1) + (p2 + p3);
#pragma unroll
            for (int off = 1; off < 16; off <<= 1) {
                za_t += __shfl_xor(za_t, off);
                zm_t += __shfl_xor(zm_t, off);
            }
            Za[r] = Za[r] * alpha + za_t;
            Zm[r] = Zm[r] * alpha + zm_t;
            mx[r] = mxn;
#pragma unroll
            for (int j = 0; j < 16; ++j) zacc[r][j] *= alpha;
            float4 pv = make_float4(p0, p1, p2, p3);
            *(float4*)&Ps[r * 16 + ty][tx * 4] = pv;   // row-permuted layout
        }

        // z' += p @ h, chunked over d
        for (int dc = 0; dc < 4; ++dc) {
            __syncthreads();
#pragma unroll
            for (int i = 0; i < 4; ++i) {
                int nl = (t >> 4) + 16 * i;
                int d4 = t & 15;
                float4 v = *(const float4*)(hb + (size_t)(n0 + nl) * D + dc * 64 + d4 * 4);
                Bs[d4*4+0][nl] = v.x; Bs[d4*4+1][nl] = v.y;
                Bs[d4*4+2][nl] = v.z; Bs[d4*4+3][nl] = v.w;
            }
            __syncthreads();
#pragma unroll 4
            for (int n4 = 0; n4 < 16; ++n4) {
                float4 p4[4];
#pragma unroll
                for (int r = 0; r < 4; ++r)
                    p4[r] = *(const float4*)&Ps[r * 16 + ty][n4 * 4];
#pragma unroll
                for (int c = 0; c < 4; ++c) {
                    float4 h4 = *(const float4*)&Bs[tx + 16 * c][n4 * 4];
#pragma unroll
                    for (int r = 0; r < 4; ++r) {
                        zacc[r][dc*4+c] = fmaf(p4[r].x, h4.x,
                                          fmaf(p4[r].y, h4.y,
                                          fmaf(p4[r].z, h4.z,
                                          fmaf(p4[r].w, h4.w, zacc[r][dc*4+c]))));
                    }
                }
            }
        }
    }

    // epilogue: normalize exactly like the reference (EPS couples to unmasked Z)
#pragma unroll
    for (int r = 0; r < 4; ++r) {
        const int a = a0 + ty * 4 + r;
        float denom = Zm[r] + EPS * Za[r];
        float inv = 1.0f / denom;
        float* zr = zout + (((size_t)b * NH + hh) * AG + a) * D;
#pragma unroll
        for (int dc = 0; dc < 4; ++dc)
#pragma unroll
            for (int c = 0; c < 4; ++c)
                zr[dc * 64 + tx + 16 * c] = zacc[r][dc*4+c] * inv;
    }
}

// ---------------------------------------------------------------------------
// Output kernel: out[b,a,e] = (1/8) * sum_{h,d} z'[b,h,a,d] * WV[h,d,e]
// NN GEMM with K = 2048 (h-major chunks of 32).
// ---------------------------------------------------------------------------
__global__ __launch_bounds__(256) void out_kernel(
    const float* __restrict__ zall, const float* __restrict__ WV,
    float* __restrict__ out)
{
    __shared__ float AsT[32][68];   // [k][row a]
    __shared__ float BsT[32][68];   // [k][col e]
    const int t  = threadIdx.x;
    const int tx = t & 15, ty = t >> 4;
    const int e0 = blockIdx.x * 64;
    const int a0 = blockIdx.y * 64;
    const int b  = blockIdx.z;

    float acc[4][4];
#pragma unroll
    for (int r = 0; r < 4; ++r)
#pragma unroll
        for (int c = 0; c < 4; ++c) acc[r][c] = 0.f;

    for (int ch = 0; ch < 64; ++ch) {
        const int hidx = ch >> 3;
        const int d0   = (ch & 7) * 32;
        __syncthreads();
#pragma unroll
        for (int ss = 0; ss < 2; ++ss) {
            int flat = t + 256 * ss;
            int rr = flat >> 3;
            int k4 = flat & 7;
            float4 v = *(const float4*)(zall +
                (((size_t)b * NH + hidx) * AG + a0 + rr) * D + d0 + k4 * 4);
            AsT[k4*4+0][rr] = v.x; AsT[k4*4+1][rr] = v.y;
            AsT[k4*4+2][rr] = v.z; AsT[k4*4+3][rr] = v.w;
            int kk = flat >> 4;      // 0..31
            int c4 = flat & 15;      // 0..15
            float4 w = *(const float4*)(WV + ((size_t)hidx * D + d0 + kk) * D + e0 + c4 * 4);
            *(float4*)&BsT[kk][c4 * 4] = w;
        }
        __syncthreads();
#pragma unroll 8
        for (int kk = 0; kk < 32; ++kk) {
            float4 a4 = *(const float4*)&AsT[kk][ty * 4];
            float4 b4 = *(const float4*)&BsT[kk][tx * 4];
            const float ar[4] = {a4.x, a4.y, a4.z, a4.w};
            const float bc[4] = {b4.x, b4.y, b4.z, b4.w};
#pragma unroll
            for (int r = 0; r < 4; ++r)
#pragma unroll
                for (int c = 0; c < 4; ++c)
                    acc[r][c] = fmaf(ar[r], bc[c], acc[r][c]);
        }
    }
#pragma unroll
    for (int r = 0; r < 4; ++r) {
        float4 o;
        o.x = acc[r][0] * 0.125f; o.y = acc[r][1] * 0.125f;
        o.z = acc[r][2] * 0.125f; o.w = acc[r][3] * 0.125f;
        *(float4*)(out + ((size_t)b * AG + a0 + ty * 4 + r) * D + e0 + tx * 4) = o;
    }
}

// ---------------------------------------------------------------------------
extern "C" void kernel_launch(void* const* d_in, const int* in_sizes, int n_in,
                              void* d_out, int out_size, void* d_ws, size_t ws_size,
                              hipStream_t stream)
{
    (void)in_sizes; (void)n_in; (void)out_size; (void)ws_size;
    const float* x     = (const float*)d_in[0];
    const float* m     = (const float*)d_in[1];
    const float* W_enc = (const float*)d_in[2];
    const float* b_enc = (const float*)d_in[3];
    const float* WQ    = (const float*)d_in[4];
    const float* WK    = (const float*)d_in[5];
    const float* WV    = (const float*)d_in[6];
    float* out = (float*)d_out;
    float* ws  = (float*)d_ws;
    float* hbuf = ws + H_OFF;   // 32 MB
    float* Mbuf = ws + M_OFF;   // 2 MB
    float* zbuf = ws + Z_OFF;   // 64 MB   (needs ws_size >= ~98 MB)

    // K1: h = lrelu(x) @ W_enc^T + b_enc      (32768 x 256, K=256)
    gemm_nt64<true, true><<<dim3(4, 512, 1), dim3(256), 0, stream>>>(
        x, W_enc, b_enc, hbuf, 0, 0, 0);

    // K2: M_h = WQ_h @ WK_h^T                 (8 x 256 x 256, K=256)
    gemm_nt64<false, false><<<dim3(4, 4, NH), dim3(256), 0, stream>>>(
        WQ, WK, nullptr, Mbuf, (size_t)D * D, (size_t)D * D, (size_t)D * D);

    // K3: fused Q' + flash attention -> z'
    attn_kernel<<<dim3(4, NH, B_N), dim3(256), 0, stream>>>(hbuf, Mbuf, m, zbuf);

    // K4: out = (1/8) z' @ WV                 (K = 2048)
    out_kernel<<<dim3(4, 4, B_N), dim3(256), 0, stream>>>(zbuf, WV, out);
}

// Round 2
// 826.828 us; speedup vs baseline: 1.8892x; 1.8892x over previous
//
#include <hip/hip_runtime.h>
#include <math.h>

namespace {
constexpr int B_N  = 32;
constexpr int SEQ  = 1024;
constexpr int AG   = 256;
constexpr int D    = 256;
constexpr int NH   = 8;
constexpr float SCALE = 0.0625f;
constexpr float EPS   = 1e-12f;

// workspace byte offsets
constexpr size_t HHI_OFF  = 0;                       // ushort B*SEQ*D   = 16 MB
constexpr size_t HLO_OFF  = 16777216;                // ushort B*SEQ*D   = 16 MB
constexpr size_t HT_OFF   = 33554432;                // ushort B*D*SEQ   = 16 MB
constexpr size_t MTHI_OFF = 50331648;                // ushort NH*D*D    = 1 MB
constexpr size_t MTLO_OFF = 51380224;                // ushort NH*D*D    = 1 MB
constexpr size_t MB_OFF   = 52428800;                // u32 B*AG*SEQ/32  = 1 MB
constexpr size_t ZB_OFF   = 53477376;                // float B*NH*AG*D  = 64 MB
}

typedef __attribute__((ext_vector_type(8))) short short8;
typedef __attribute__((ext_vector_type(4))) float floatx4;
#define MFMA16(A,B,C) __builtin_amdgcn_mfma_f32_16x16x32_bf16(A,B,C,0,0,0)

__device__ __forceinline__ unsigned short bf16_rtne(float f) {
    unsigned u = __float_as_uint(f);
    u += 0x7fffu + ((u >> 16) & 1u);
    return (unsigned short)(u >> 16);
}
__device__ __forceinline__ float bf16_tof(unsigned short h) {
    return __uint_as_float(((unsigned)h) << 16);
}

// ---------------------------------------------------------------------------
// Encoder: h = lrelu(x) @ W_enc^T + b_enc -> h_hi, h_lo [B,N,D], hT_hi [B,D,N]
// ---------------------------------------------------------------------------
__global__ __launch_bounds__(256) void enc_kernel(
    const float* __restrict__ x, const float* __restrict__ W_enc,
    const float* __restrict__ b_enc,
    ushort* __restrict__ h_hi, ushort* __restrict__ h_lo, ushort* __restrict__ hT)
{
    __shared__ float AsT[32][68];
    __shared__ float BsT[32][68];
    const int t  = threadIdx.x;
    const int tx = t & 15, ty = t >> 4;
    const int col0 = blockIdx.x * 64;
    const int row0 = blockIdx.y * 64;

    float acc[4][4];
#pragma unroll
    for (int r = 0; r < 4; ++r)
#pragma unroll
        for (int c = 0; c < 4; ++c) acc[r][c] = 0.f;

    for (int k0 = 0; k0 < 256; k0 += 32) {
        __syncthreads();
#pragma unroll
        for (int ss = 0; ss < 2; ++ss) {
            int flat = t + 256 * ss;
            int rr = flat >> 3, k4 = flat & 7;
            float4 v = *(const float4*)(x + (size_t)(row0 + rr) * 256 + k0 + k4 * 4);
            v.x = v.x > 0.f ? v.x : 0.01f * v.x;
            v.y = v.y > 0.f ? v.y : 0.01f * v.y;
            v.z = v.z > 0.f ? v.z : 0.01f * v.z;
            v.w = v.w > 0.f ? v.w : 0.01f * v.w;
            AsT[k4*4+0][rr] = v.x; AsT[k4*4+1][rr] = v.y;
            AsT[k4*4+2][rr] = v.z; AsT[k4*4+3][rr] = v.w;
            float4 wv = *(const float4*)(W_enc + (size_t)(col0 + rr) * 256 + k0 + k4 * 4);
            BsT[k4*4+0][rr] = wv.x; BsT[k4*4+1][rr] = wv.y;
            BsT[k4*4+2][rr] = wv.z; BsT[k4*4+3][rr] = wv.w;
        }
        __syncthreads();
#pragma unroll 8
        for (int kk = 0; kk < 32; ++kk) {
            float4 a4 = *(const float4*)&AsT[kk][ty * 4];
            float4 b4 = *(const float4*)&BsT[kk][tx * 4];
            const float ar[4] = {a4.x, a4.y, a4.z, a4.w};
            const float bc[4] = {b4.x, b4.y, b4.z, b4.w};
#pragma unroll
            for (int r = 0; r < 4; ++r)
#pragma unroll
                for (int c = 0; c < 4; ++c)
                    acc[r][c] = fmaf(ar[r], bc[c], acc[r][c]);
        }
    }

    float4 bv = *(const float4*)(b_enc + col0 + tx * 4);
    const float bb4[4] = {bv.x, bv.y, bv.z, bv.w};
#pragma unroll
    for (int r = 0; r < 4; ++r) {
        const int row = row0 + ty * 4 + r;
        const int bb = row >> 10, nn = row & 1023;
        ushort hi4[4], lo4[4];
#pragma unroll
        for (int c = 0; c < 4; ++c) {
            float v = acc[r][c] + bb4[c];
            hi4[c] = bf16_rtne(v);
            lo4[c] = bf16_rtne(v - bf16_tof(hi4[c]));
        }
        *(ushort4*)(h_hi + (size_t)row * 256 + col0 + tx * 4) =
            make_ushort4(hi4[0], hi4[1], hi4[2], hi4[3]);
        *(ushort4*)(h_lo + (size_t)row * 256 + col0 + tx * 4) =
            make_ushort4(lo4[0], lo4[1], lo4[2], lo4[3]);
#pragma unroll
        for (int c = 0; c < 4; ++c)
            hT[((size_t)(bb * 256 + col0 + tx * 4 + c)) * 1024 + nn] = hi4[c];
    }
}

// ---------------------------------------------------------------------------
// Mt_h[d'][d] = (WQ_h @ WK_h^T)[d][d'] = sum_e WK[d',e] * WQ[d,e]  -> hi/lo
// ---------------------------------------------------------------------------
__global__ __launch_bounds__(256) void mprep_kernel(
    const float* __restrict__ WQ, const float* __restrict__ WK,
    ushort* __restrict__ Mt_hi, ushort* __restrict__ Mt_lo)
{
    __shared__ float AsT[32][68];
    __shared__ float BsT[32][68];
    const int t  = threadIdx.x;
    const int tx = t & 15, ty = t >> 4;
    const int col0 = blockIdx.x * 64;   // d
    const int row0 = blockIdx.y * 64;   // d'
    const float* A  = WK + (size_t)blockIdx.z * 256 * 256;
    const float* Bm = WQ + (size_t)blockIdx.z * 256 * 256;
    ushort* Chi = Mt_hi + (size_t)blockIdx.z * 256 * 256;
    ushort* Clo = Mt_lo + (size_t)blockIdx.z * 256 * 256;

    float acc[4][4];
#pragma unroll
    for (int r = 0; r < 4; ++r)
#pragma unroll
        for (int c = 0; c < 4; ++c) acc[r][c] = 0.f;

    for (int k0 = 0; k0 < 256; k0 += 32) {
        __syncthreads();
#pragma unroll
        for (int ss = 0; ss < 2; ++ss) {
            int flat = t + 256 * ss;
            int rr = flat >> 3, k4 = flat & 7;
            float4 v = *(const float4*)(A + (size_t)(row0 + rr) * 256 + k0 + k4 * 4);
            AsT[k4*4+0][rr] = v.x; AsT[k4*4+1][rr] = v.y;
            AsT[k4*4+2][rr] = v.z; AsT[k4*4+3][rr] = v.w;
            float4 wv = *(const float4*)(Bm + (size_t)(col0 + rr) * 256 + k0 + k4 * 4);
            BsT[k4*4+0][rr] = wv.x; BsT[k4*4+1][rr] = wv.y;
            BsT[k4*4+2][rr] = wv.z; BsT[k4*4+3][rr] = wv.w;
        }
        __syncthreads();
#pragma unroll 8
        for (int kk = 0; kk < 32; ++kk) {
            float4 a4 = *(const float4*)&AsT[kk][ty * 4];
            float4 b4 = *(const float4*)&BsT[kk][tx * 4];
            const float ar[4] = {a4.x, a4.y, a4.z, a4.w};
            const float bc[4] = {b4.x, b4.y, b4.z, b4.w};
#pragma unroll
            for (int r = 0; r < 4; ++r)
#pragma unroll
                for (int c = 0; c < 4; ++c)
                    acc[r][c] = fmaf(ar[r], bc[c], acc[r][c]);
        }
    }
#pragma unroll
    for (int r = 0; r < 4; ++r) {
        const int row = row0 + ty * 4 + r;
        ushort hi4[4], lo4[4];
#pragma unroll
        for (int c = 0; c < 4; ++c) {
            float v = acc[r][c];
            hi4[c] = bf16_rtne(v);
            lo4[c] = bf16_rtne(v - bf16_tof(hi4[c]));
        }
        *(ushort4*)(Chi + (size_t)row * 256 + col0 + tx * 4) =
            make_ushort4(hi4[0], hi4[1], hi4[2], hi4[3]);
        *(ushort4*)(Clo + (size_t)row * 256 + col0 + tx * 4) =
            make_ushort4(lo4[0], lo4[1], lo4[2], lo4[3]);
    }
}

// ---------------------------------------------------------------------------
// mask -> bitmask (1 bit per element, word = n/32, bit = n%32)
// ---------------------------------------------------------------------------
__global__ __launch_bounds__(256) void maskbits_kernel(
    const float* __restrict__ m, unsigned* __restrict__ mb)
{
    const int idx = blockIdx.x * 256 + threadIdx.x;   // word index
    const float4* src = (const float4*)(m + (size_t)idx * 32);
    unsigned wbits = 0;
#pragma unroll
    for (int i = 0; i < 8; ++i) {
        float4 v = src[i];
        wbits |= (v.x > 0.5f ? 1u : 0u) << (i * 4 + 0);
        wbits |= (v.y > 0.5f ? 1u : 0u) << (i * 4 + 1);
        wbits |= (v.z > 0.5f ? 1u : 0u) << (i * 4 + 2);
        wbits |= (v.w > 0.5f ? 1u : 0u) << (i * 4 + 3);
    }
    mb[idx] = wbits;
}

// ---------------------------------------------------------------------------
// Attention (MFMA): block = (a-tile 64, head, batch); 4 waves x 16 a-rows.
// Phase 0: Q' = ha @ Mt^T via split-bf16 MFMA (3x), repack to A-frags via LDS.
// Phase 1: flash loop (16 n-tiles of 64): S (3x MFMA), online masked softmax,
//          z += p @ h (1x MFMA, hT layout). LDS 72.7 KB -> 2 blocks/CU.
// ---------------------------------------------------------------------------
__global__ __launch_bounds__(256, 2) void attn_mfma(
    const ushort* __restrict__ h_hi, const ushort* __restrict__ h_lo,
    const ushort* __restrict__ hT,   const ushort* __restrict__ Mt_hi,
    const ushort* __restrict__ Mt_lo, const unsigned* __restrict__ mbits,
    float* __restrict__ zout)
{
    __shared__ ushort hS_hi[64][72];
    __shared__ ushort hS_lo[64][72];
    __shared__ ushort hTs[256][72];
    __shared__ float  pS[64][68];

    const int t    = threadIdx.x;
    const int wv   = t >> 6;
    const int lane = t & 63;
    const int l15  = lane & 15;
    const int quad = lane >> 4;
    const int a0 = blockIdx.x * 64;
    const int hh = blockIdx.y;
    const int b  = blockIdx.z;
    const int aw = a0 + wv * 16;

    const ushort* hb_hi = h_hi + (size_t)b * SEQ * D;
    const ushort* hb_lo = h_lo + (size_t)b * SEQ * D;
    const ushort* hTb   = hT   + (size_t)b * D * SEQ;

    // ---- Phase 0: Q' tiles (C-layout), 16 d'-tiles
    floatx4 qac[16];
#pragma unroll
    for (int i = 0; i < 16; ++i) qac[i] = (floatx4){0.f, 0.f, 0.f, 0.f};

    for (int kc = 0; kc < 4; ++kc) {
        short8 Ah[2], Al[2];
#pragma unroll
        for (int kt = 0; kt < 2; ++kt) {
            const size_t ao = (size_t)(aw + l15) * D + kc * 64 + kt * 32 + quad * 8;
            Ah[kt] = *(const short8*)(hb_hi + ao);
            Al[kt] = *(const short8*)(hb_lo + ao);
        }
#pragma unroll
        for (int nt2 = 0; nt2 < 16; ++nt2) {
#pragma unroll
            for (int kt = 0; kt < 2; ++kt) {
                const size_t mo = ((size_t)hh * D + nt2 * 16 + l15) * D +
                                  kc * 64 + kt * 32 + quad * 8;
                short8 Bh = *(const short8*)(Mt_hi + mo);
                short8 Bl = *(const short8*)(Mt_lo + mo);
                qac[nt2] = MFMA16(Ah[kt], Bh, qac[nt2]);
                qac[nt2] = MFMA16(Al[kt], Bh, qac[nt2]);
                qac[nt2] = MFMA16(Ah[kt], Bl, qac[nt2]);
            }
        }
    }

    // repack Q' C-layout -> A-frag layout (hi/lo) via per-wave LDS region
    short8 Qhi[8], Qlo[8];
    for (int c = 0; c < 4; ++c) {
        __syncthreads();
#pragma unroll
        for (int j = 0; j < 4; ++j)
#pragma unroll
            for (int r = 0; r < 4; ++r)
                pS[wv * 16 + quad * 4 + r][j * 16 + l15] = qac[c * 4 + j][r];
        __syncthreads();
#pragma unroll
        for (int kt = 0; kt < 2; ++kt) {
            const float* pr = &pS[wv * 16 + l15][kt * 32 + quad * 8];
            float f[8];
            *(float4*)&f[0] = *(const float4*)pr;
            *(float4*)&f[4] = *(const float4*)(pr + 4);
            short8 hi, lo;
#pragma unroll
            for (int e = 0; e < 8; ++e) {
                unsigned short hb = bf16_rtne(f[e]);
                hi[e] = (short)hb;
                lo[e] = (short)bf16_rtne(f[e] - bf16_tof(hb));
            }
            Qhi[c * 2 + kt] = hi;
            Qlo[c * 2 + kt] = lo;
        }
    }

    // ---- Phase 1: flash loop
    floatx4 zac[16];
#pragma unroll
    for (int i = 0; i < 16; ++i) zac[i] = (floatx4){0.f, 0.f, 0.f, 0.f};
    float mx[4] = {-INFINITY, -INFINITY, -INFINITY, -INFINITY};
    float Za[4] = {0.f, 0.f, 0.f, 0.f};
    float Zm[4] = {0.f, 0.f, 0.f, 0.f};

    for (int nt = 0; nt < 16; ++nt) {
        const int n0 = nt * 64;
        floatx4 sac[4];
#pragma unroll
        for (int i = 0; i < 4; ++i) sac[i] = (floatx4){0.f, 0.f, 0.f, 0.f};

        for (int kc = 0; kc < 4; ++kc) {
            __syncthreads();
#pragma unroll
            for (int it = 0; it < 2; ++it) {
                const int g = t + it * 256;
                const int row = g >> 3, cc = g & 7;
                const size_t so = (size_t)(n0 + row) * D + kc * 64 + cc * 8;
                *(short8*)&hS_hi[row][cc * 8] = *(const short8*)(hb_hi + so);
                *(short8*)&hS_lo[row][cc * 8] = *(const short8*)(hb_lo + so);
                *(short8*)&hTs[kc * 64 + row][cc * 8] =
                    *(const short8*)(hTb + (size_t)(kc * 64 + row) * SEQ + n0 + cc * 8);
            }
            __syncthreads();
#pragma unroll
            for (int kt = 0; kt < 2; ++kt) {
                const int ks = kc * 2 + kt;
#pragma unroll
                for (int ntile = 0; ntile < 4; ++ntile) {
                    short8 Bh = *(const short8*)&hS_hi[ntile * 16 + l15][kt * 32 + quad * 8];
                    short8 Bl = *(const short8*)&hS_lo[ntile * 16 + l15][kt * 32 + quad * 8];
                    sac[ntile] = MFMA16(Qhi[ks], Bh, sac[ntile]);
                    sac[ntile] = MFMA16(Qlo[ks], Bh, sac[ntile]);
                    sac[ntile] = MFMA16(Qhi[ks], Bl, sac[ntile]);
                }
            }
        }

        // online masked softmax (row a = a0 + 16*wv + 4*quad + r)
        float alr[4];
#pragma unroll
        for (int r = 0; r < 4; ++r) {
            const int a = a0 + wv * 16 + quad * 4 + r;
            const unsigned* mw = mbits + ((size_t)b * AG + a) * (SEQ / 32) + (n0 >> 5);
            const unsigned w0 = mw[0], w1 = mw[1];
            float l0 = sac[0][r] * SCALE, l1 = sac[1][r] * SCALE;
            float l2 = sac[2][r] * SCALE, l3 = sac[3][r] * SCALE;
            float mt = fmaxf(fmaxf(l0, l1), fmaxf(l2, l3));
#pragma unroll
            for (int off = 1; off < 16; off <<= 1) mt = fmaxf(mt, __shfl_xor(mt, off));
            const float mxn = fmaxf(mx[r], mt);
            const float al  = __expf(mx[r] - mxn);
            float e0 = __expf(l0 - mxn), e1 = __expf(l1 - mxn);
            float e2 = __expf(l2 - mxn), e3 = __expf(l3 - mxn);
            float p0 = ((w0 >> l15) & 1u)        ? e0 : 0.f;
            float p1 = ((w0 >> (16 + l15)) & 1u) ? e1 : 0.f;
            float p2 = ((w1 >> l15) & 1u)        ? e2 : 0.f;
            float p3 = ((w1 >> (16 + l15)) & 1u) ? e3 : 0.f;
            float za = (e0 + e1) + (e2 + e3);
            float zm = (p0 + p1) + (p2 + p3);
#pragma unroll
            for (int off = 1; off < 16; off <<= 1) {
                za += __shfl_xor(za, off);
                zm += __shfl_xor(zm, off);
            }
            Za[r] = Za[r] * al + za;
            Zm[r] = Zm[r] * al + zm;
            mx[r] = mxn;
            pS[wv * 16 + quad * 4 + r][l15]      = p0;
            pS[wv * 16 + quad * 4 + r][16 + l15] = p1;
            pS[wv * 16 + quad * 4 + r][32 + l15] = p2;
            pS[wv * 16 + quad * 4 + r][48 + l15] = p3;
            alr[r] = al;
        }
#pragma unroll
        for (int dt = 0; dt < 16; ++dt) {
            zac[dt][0] *= alr[0]; zac[dt][1] *= alr[1];
            zac[dt][2] *= alr[2]; zac[dt][3] *= alr[3];
        }
        __syncthreads();

        // z += p @ h  (p A-frags from LDS, h B-frags from hT slab)
        short8 Pf[2];
#pragma unroll
        for (int kt = 0; kt < 2; ++kt) {
            const float* pr = &pS[wv * 16 + l15][kt * 32 + quad * 8];
            float f[8];
            *(float4*)&f[0] = *(const float4*)pr;
            *(float4*)&f[4] = *(const float4*)(pr + 4);
            short8 s;
#pragma unroll
            for (int e = 0; e < 8; ++e) s[e] = (short)bf16_rtne(f[e]);
            Pf[kt] = s;
        }
#pragma unroll
        for (int dt = 0; dt < 16; ++dt) {
#pragma unroll
            for (int kt = 0; kt < 2; ++kt) {
                short8 Bh = *(const short8*)&hTs[dt * 16 + l15][kt * 32 + quad * 8];
                zac[dt] = MFMA16(Pf[kt], Bh, zac[dt]);
            }
        }
    }

    // epilogue: z / (Zm + EPS*Za)
#pragma unroll
    for (int r = 0; r < 4; ++r) {
        const int a = a0 + wv * 16 + quad * 4 + r;
        const float inv = 1.0f / (Zm[r] + EPS * Za[r]);
        float* zr = zout + (((size_t)b * NH + hh) * AG + a) * D;
#pragma unroll
        for (int dt = 0; dt < 16; ++dt)
            zr[dt * 16 + l15] = zac[dt][r] * inv;
    }
}

// ---------------------------------------------------------------------------
// out[b,a,e] = (1/8) * sum_{h,d} z'[b,h,a,d] * WV[h,d,e]   (K = 2048)
// ---------------------------------------------------------------------------
__global__ __launch_bounds__(256) void out_kernel(
    const float* __restrict__ zall, const float* __restrict__ WV,
    float* __restrict__ out)
{
    __shared__ float AsT[32][68];
    __shared__ float BsT[32][68];
    const int t  = threadIdx.x;
    const int tx = t & 15, ty = t >> 4;
    const int e0 = blockIdx.x * 64;
    const int a0 = blockIdx.y * 64;
    const int b  = blockIdx.z;

    float acc[4][4];
#pragma unroll
    for (int r = 0; r < 4; ++r)
#pragma unroll
        for (int c = 0; c < 4; ++c) acc[r][c] = 0.f;

    for (int ch = 0; ch < 64; ++ch) {
        const int hidx = ch >> 3;
        const int d0   = (ch & 7) * 32;
        __syncthreads();
#pragma unroll
        for (int ss = 0; ss < 2; ++ss) {
            int flat = t + 256 * ss;
            int rr = flat >> 3, k4 = flat & 7;
            float4 v = *(const float4*)(zall +
                (((size_t)b * NH + hidx) * AG + a0 + rr) * D + d0 + k4 * 4);
            AsT[k4*4+0][rr] = v.x; AsT[k4*4+1][rr] = v.y;
            AsT[k4*4+2][rr] = v.z; AsT[k4*4+3][rr] = v.w;
            int kk = flat >> 4, c4 = flat & 15;
            float4 wv = *(const float4*)(WV + ((size_t)hidx * D + d0 + kk) * D + e0 + c4 * 4);
            *(float4*)&BsT[kk][c4 * 4] = wv;
        }
        __syncthreads();
#pragma unroll 8
        for (int kk = 0; kk < 32; ++kk) {
            float4 a4 = *(const float4*)&AsT[kk][ty * 4];
            float4 b4 = *(const float4*)&BsT[kk][tx * 4];
            const float ar[4] = {a4.x, a4.y, a4.z, a4.w};
            const float bc[4] = {b4.x, b4.y, b4.z, b4.w};
#pragma unroll
            for (int r = 0; r < 4; ++r)
#pragma unroll
                for (int c = 0; c < 4; ++c)
                    acc[r][c] = fmaf(ar[r], bc[c], acc[r][c]);
        }
    }
#pragma unroll
    for (int r = 0; r < 4; ++r) {
        float4 o;
        o.x = acc[r][0] * 0.125f; o.y = acc[r][1] * 0.125f;
        o.z = acc[r][2] * 0.125f; o.w = acc[r][3] * 0.125f;
        *(float4*)(out + ((size_t)b * AG + a0 + ty * 4 + r) * D + e0 + tx * 4) = o;
    }
}

// ---------------------------------------------------------------------------
extern "C" void kernel_launch(void* const* d_in, const int* in_sizes, int n_in,
                              void* d_out, int out_size, void* d_ws, size_t ws_size,
                              hipStream_t stream)
{
    (void)in_sizes; (void)n_in; (void)out_size; (void)ws_size;
    const float* x     = (const float*)d_in[0];
    const float* m     = (const float*)d_in[1];
    const float* W_enc = (const float*)d_in[2];
    const float* b_enc = (const float*)d_in[3];
    const float* WQ    = (const float*)d_in[4];
    const float* WK    = (const float*)d_in[5];
    const float* WV    = (const float*)d_in[6];
    float* out = (float*)d_out;
    char* ws = (char*)d_ws;

    ushort*   h_hi  = (ushort*)(ws + HHI_OFF);
    ushort*   h_lo  = (ushort*)(ws + HLO_OFF);
    ushort*   hT    = (ushort*)(ws + HT_OFF);
    ushort*   Mt_hi = (ushort*)(ws + MTHI_OFF);
    ushort*   Mt_lo = (ushort*)(ws + MTLO_OFF);
    unsigned* mbits = (unsigned*)(ws + MB_OFF);
    float*    zbuf  = (float*)(ws + ZB_OFF);

    enc_kernel<<<dim3(4, 512, 1), dim3(256), 0, stream>>>(
        x, W_enc, b_enc, h_hi, h_lo, hT);
    mprep_kernel<<<dim3(4, 4, NH), dim3(256), 0, stream>>>(WQ, WK, Mt_hi, Mt_lo);
    maskbits_kernel<<<dim3(1024, 1, 1), dim3(256), 0, stream>>>(m, mbits);
    attn_mfma<<<dim3(4, NH, B_N), dim3(256), 0, stream>>>(
        h_hi, h_lo, hT, Mt_hi, Mt_lo, mbits, zbuf);
    out_kernel<<<dim3(4, 4, B_N), dim3(256), 0, stream>>>(zbuf, WV, out);
}